// Round 3
// baseline (505.978 us; speedup 1.0000x reference)
//
#include <hip/hip_runtime.h>

#define SEQ 2048
#define BATCH 16
#define DMODEL 512
#define FFDIM 2048
#define NTOK (SEQ * BATCH) /* 32768 tokens */
#define ALPHA 0.9f

typedef unsigned short u16;
typedef unsigned int u32;
typedef __attribute__((ext_vector_type(8))) short short8;
typedef __attribute__((ext_vector_type(4))) float f32x4;

__device__ __forceinline__ float bf2f(u16 u) {
    unsigned int v = ((unsigned int)u) << 16;
    return __builtin_bit_cast(float, v);
}
__device__ __forceinline__ u16 f2bf(float f) {
    unsigned int v = __builtin_bit_cast(unsigned int, f);
    v += 0x7fffu + ((v >> 16) & 1u);   // RNE
    return (u16)(v >> 16);
}

// ---------------------------------------------------------------------------
// fp32 -> bf16 conversion (weights), 4 elems/thread
// ---------------------------------------------------------------------------
__global__ __launch_bounds__(256) void cvt_kernel(const float* __restrict__ in,
                                                  u16* __restrict__ out, int n) {
    const int i = (blockIdx.x * 256 + threadIdx.x) * 4;
    if (i >= n) return;
    float4 v = *(const float4*)(in + i);
    ushort4 o;
    o.x = f2bf(v.x); o.y = f2bf(v.y); o.z = f2bf(v.z); o.w = f2bf(v.w);
    *(ushort4*)(out + i) = o;
}

// ---------------------------------------------------------------------------
// LayerNorm (used only for LN1): one wave per token
// ---------------------------------------------------------------------------
__global__ __launch_bounds__(256) void ln_kernel(const float* __restrict__ xin,
                                                 const float* __restrict__ g,
                                                 const float* __restrict__ b,
                                                 u16* __restrict__ y) {
    const int lane = threadIdx.x & 63;
    const int wave = threadIdx.x >> 6;
    const long tok = (long)blockIdx.x * 4 + wave;
    const long off = tok * DMODEL + lane * 8;

    float f[8];
    {
        const float4* xp = (const float4*)(xin + off);
        float4 a = xp[0], c = xp[1];
        f[0] = a.x; f[1] = a.y; f[2] = a.z; f[3] = a.w;
        f[4] = c.x; f[5] = c.y; f[6] = c.z; f[7] = c.w;
    }
    float s = 0.f, s2 = 0.f;
#pragma unroll
    for (int i = 0; i < 8; i++) { s += f[i]; s2 += f[i] * f[i]; }
#pragma unroll
    for (int o = 32; o > 0; o >>= 1) {
        s += __shfl_xor(s, o, 64);
        s2 += __shfl_xor(s2, o, 64);
    }
    const float mean = s * (1.f / DMODEL);
    const float var = s2 * (1.f / DMODEL) - mean * mean;
    const float inv = rsqrtf(var + 1e-5f);

    const float4* gp = (const float4*)(g + lane * 8);
    const float4* bp = (const float4*)(b + lane * 8);
    float4 g0 = gp[0], g1 = gp[1], b0 = bp[0], b1 = bp[1];
    float gg[8] = {g0.x, g0.y, g0.z, g0.w, g1.x, g1.y, g1.z, g1.w};
    float bb[8] = {b0.x, b0.y, b0.z, b0.w, b1.x, b1.y, b1.z, b1.w};
    short8 ov;
#pragma unroll
    for (int i = 0; i < 8; i++)
        ov[i] = (short)f2bf((f[i] - mean) * inv * gg[i] + bb[i]);
    *(short8*)(y + off) = ov;
}

// ---------------------------------------------------------------------------
// Fused scan + LN2: block = (batch b, s-chunk). 256 threads, 2 d's per thread
// (d = 2t, 2t+1) -> one block owns a token's full 512-d row.
// Per token s: x1 = x + attn (exp-decay scan), block-reduce mean/var over 512,
// write x1 (fp32, FF2 residual) and y = LN(x1) (bf16, FF1 input).
// Pipeline discipline: 4-deep register prefetch of z/x; raw s_barrier (NOT
// __syncthreads -> would drain vmcnt(0) per token); lgkmcnt(0) before barrier
// orders the LDS reduce write; global loads stay in flight across barriers.
// ---------------------------------------------------------------------------
#define SCAN_L 128
#define SCAN_H 160
__global__ __launch_bounds__(256) void scan_ln_kernel(const u16* __restrict__ z,
                                                      const float* __restrict__ x,
                                                      const float* __restrict__ g,
                                                      const float* __restrict__ be,
                                                      float* __restrict__ x1,
                                                      u16* __restrict__ y) {
    __shared__ float red[2][4][2];  // [slot][wave][sum,sumsq]
    const int t = threadIdx.x;
    const int lane = t & 63, wave = t >> 6;
    const int b = blockIdx.x;             // 0..15
    const int s0 = blockIdx.y * SCAN_L;   // s-chunk base
    const int d0 = 2 * t;

    const u32* zp = (const u32*)z;        // 2 bf16 per u32
    const float2* xp = (const float2*)x;
    float2* x1p = (float2*)x1;
    u32* yp = (u32*)y;
    const int colu = b * 256 + t;         // column in u32/float2 units (row stride 4096)

    const float gg0 = g[d0], gg1 = g[d0 + 1];
    const float bb0 = be[d0], bb1 = be[d0 + 1];

    // ---- warm-up scan (alpha^160 ~ 5e-8) ----
    float r0 = 0.f, r1 = 0.f;
    {
        int s = s0 - SCAN_H;
        if (s < 0) s = 0;
        for (; s < s0; ++s) {
            const u32 zz = zp[(long)s * 4096 + colu];
            r0 = ALPHA * (bf2f((u16)(zz & 0xffffu)) + r0);
            r1 = ALPHA * (bf2f((u16)(zz >> 16)) + r1);
        }
    }
    float ap = powf(ALPHA, (float)(s0 + 2));  // alpha^{s0+2}

    // ---- 4-deep prefetch queues (statically indexed via unroll-4) ----
    u32 zq[4];
    float2 xq[4];
#pragma unroll
    for (int j = 0; j < 4; j++) {
        zq[j] = zp[(long)(s0 + j) * 4096 + colu];
        xq[j] = xp[(long)(s0 + j) * 4096 + colu];
    }

#pragma unroll 4
    for (int i = 0; i < SCAN_L; i++) {
        const int sl = i & 3;  // compile-time per unrolled instance
        const u32 zz = zq[sl];
        const float2 xx = xq[sl];
        if (i + 4 < SCAN_L) {
            zq[sl] = zp[(long)(s0 + i + 4) * 4096 + colu];
            xq[sl] = xp[(long)(s0 + i + 4) * 4096 + colu];
        }
        const float z0 = bf2f((u16)(zz & 0xffffu));
        const float z1 = bf2f((u16)(zz >> 16));
        r0 = ALPHA * (z0 + r0);
        r1 = ALPHA * (z1 + r1);
        const float c = 1.f - (ALPHA - ap) * 10.f;  // 10 = 1/(1-alpha)
        ap *= ALPHA;
        const float v0 = xx.x + r0 + c * z0;
        const float v1 = xx.y + r1 + c * z1;
        x1p[(long)(s0 + i) * 4096 + colu] = (float2){v0, v1};

        // ---- LN over the 512-wide row: wave shuffle + 4-partial LDS ----
        float s1 = v0 + v1, s2 = v0 * v0 + v1 * v1;
#pragma unroll
        for (int o = 32; o > 0; o >>= 1) {
            s1 += __shfl_xor(s1, o, 64);
            s2 += __shfl_xor(s2, o, 64);
        }
        const int slot = i & 1;  // 2-slot: iter i writes slot i&1; next iter's
                                 // writes hit the other slot -> no WAR race
        if (lane == 0) {
            red[slot][wave][0] = s1;
            red[slot][wave][1] = s2;
        }
        asm volatile("s_waitcnt lgkmcnt(0)" ::: "memory");
        __builtin_amdgcn_s_barrier();  // raw: prefetch loads stay in flight
        const float S = red[slot][0][0] + red[slot][1][0] + red[slot][2][0] + red[slot][3][0];
        const float S2 = red[slot][0][1] + red[slot][1][1] + red[slot][2][1] + red[slot][3][1];
        const float mean = S * (1.f / DMODEL);
        const float var = S2 * (1.f / DMODEL) - mean * mean;
        const float inv = rsqrtf(var + 1e-5f);
        const u16 o0 = f2bf((v0 - mean) * inv * gg0 + bb0);
        const u16 o1 = f2bf((v1 - mean) * inv * gg1 + bb1);
        yp[(long)(s0 + i) * 4096 + colu] = ((u32)o1 << 16) | (u32)o0;
    }
}

// ---------------------------------------------------------------------------
// GEMM 128x128 / BK=64 / 4 waves / 64 KiB LDS -> 2 blocks/CU (cross-block TLP)
//   C[M,N] = epi(A[M,K] @ Bt[N,K]^T + bias[N])
// Round-3 change: block linearization lin = bx*gy + by so consecutive blocks
// (same XCD after the bijective chunked swizzle) share m0 -> the big A-panel
// is fetched once from HBM and re-served from L2/L3 to its n-siblings.
// Kept: 3-bit octet XOR swizzle (0 bank conflicts, source+read side),
// counted vmcnt(8) depth-1 prefetch, 2 barriers/K-tile.
// EPI: 0=+bias  1=relu(+bias)  2=+bias+resid(fp32);  OUT_F32 selects store type
// ---------------------------------------------------------------------------
#define BM 128
#define BN 128
#define BKK 64

typedef __attribute__((address_space(1))) unsigned int as1_u32;
typedef __attribute__((address_space(3))) unsigned int as3_u32;

__device__ __forceinline__ void gld_lds16(const void* g, const void* l) {
    __builtin_amdgcn_global_load_lds((as1_u32*)(unsigned long long)g,
                                     (as3_u32*)(unsigned int)(unsigned long long)l,
                                     16, 0, 0);
}

template <int EPI, bool OUT_F32>
__global__ __launch_bounds__(256, 2) void gemm128(const u16* __restrict__ A,
                                                  const u16* __restrict__ Bt,
                                                  const float* __restrict__ bias,
                                                  const float* __restrict__ resid,
                                                  void* __restrict__ C,
                                                  int M, int N, int K) {
    __shared__ alignas(16) u16 sA[2][BM * BKK];   // 32 KiB
    __shared__ alignas(16) u16 sB[2][BN * BKK];   // 32 KiB

    const int tid = threadIdx.x;
    const int lane = tid & 63;
    const int wave = tid >> 6;          // 4 waves: 2M x 2N, each owns 64x64
    const int wr = wave >> 1;
    const int wc = wave & 1;
    const int l15 = lane & 15, q16 = lane >> 4;

    // T1 + A-panel sharing: consecutive lin share bx (the m-panel). XCD-chunked
    // bijective swizzle keeps each XCD's share contiguous in swz, so the
    // n-siblings of one m-panel are co-resident on one XCD -> A hits L2.
    const int gy = gridDim.y;
    const int nwg = gridDim.x * gy;
    const int lin = blockIdx.x * gy + blockIdx.y;
    const int cpx = nwg >> 3;
    const int swz = (lin & 7) * cpx + (lin >> 3);
    const int m0 = (swz / gy) * BM;
    const int n0 = (swz % gy) * BN;

    // ---- staging: 1024 octets per matrix tile, 256 thr -> 4 chunks each.
    //      LDS dest linear; global source octet pre-swizzled (rule #21). ----
    const u16* gA[4];
    const u16* gB[4];
    int ldsoff[4];
#pragma unroll
    for (int i = 0; i < 4; i++) {
        const int ch = tid + i * 256;           // 0..1023
        const int r = ch >> 3;                  // row 0..127 (8 octets/row)
        const int oo = (ch & 7) ^ (r & 7);      // swizzled source octet
        gA[i] = A + (long)(m0 + r) * K + oo * 8;
        gB[i] = Bt + (long)(n0 + r) * K + oo * 8;
        ldsoff[i] = ch * 8;                     // u16 elements
    }

    // ---- fragment read addressing (swizzled): row&7 == l15&7 for all frags ----
    const int x7 = l15 & 7;
    int octk[2];
    octk[0] = ((0 + q16) ^ x7) * 8;
    octk[1] = ((4 + q16) ^ x7) * 8;
    const int rowA0 = wr * 64 + l15;
    const int rowB0 = wc * 64 + l15;

    f32x4 acc[4][4];
#pragma unroll
    for (int i = 0; i < 4; i++)
#pragma unroll
        for (int j = 0; j < 4; j++) acc[i][j] = (f32x4){0.f, 0.f, 0.f, 0.f};

    const int NT = K / BKK;

    // prologue: stage tile 0 -> buf 0
#pragma unroll
    for (int i = 0; i < 4; i++) gld_lds16(gA[i], &sA[0][ldsoff[i]]);
#pragma unroll
    for (int i = 0; i < 4; i++) gld_lds16(gB[i], &sB[0][ldsoff[i]]);

#pragma unroll 1
    for (int t = 0; t < NT; ++t) {
        const int pb = t & 1;
        // stage t+1 into the other buffer, then counted wait for tile t.
        if (t + 1 < NT) {
            const int pn = (t + 1) & 1;
            const int ko = (t + 1) * BKK;
#pragma unroll
            for (int i = 0; i < 4; i++) gld_lds16(gA[i] + ko, &sA[pn][ldsoff[i]]);
#pragma unroll
            for (int i = 0; i < 4; i++) gld_lds16(gB[i] + ko, &sB[pn][ldsoff[i]]);
            asm volatile("s_waitcnt vmcnt(8)" ::: "memory");
        } else {
            asm volatile("s_waitcnt vmcnt(0)" ::: "memory");
        }
        __builtin_amdgcn_s_barrier();   // all waves' tile-t loads landed

        const u16* pa = &sA[pb][rowA0 * BKK];
        const u16* pbb = &sB[pb][rowB0 * BKK];

#pragma unroll
        for (int kk = 0; kk < 2; kk++) {
            short8 a[4], b[4];
#pragma unroll
            for (int i = 0; i < 4; i++)
                a[i] = *(const short8*)(pa + i * 16 * BKK + octk[kk]);
#pragma unroll
            for (int j = 0; j < 4; j++)
                b[j] = *(const short8*)(pbb + j * 16 * BKK + octk[kk]);
#pragma unroll
            for (int i = 0; i < 4; i++)
#pragma unroll
                for (int j = 0; j < 4; j++)
                    acc[i][j] = __builtin_amdgcn_mfma_f32_16x16x32_bf16(a[i], b[j],
                                                                        acc[i][j], 0, 0, 0);
        }
        __builtin_amdgcn_s_barrier();   // done reading buf[pb] before restage
    }

    // ---- epilogue: C/D layout col=lane&15, row=(lane>>4)*4+reg ----
#pragma unroll
    for (int i = 0; i < 4; i++) {
        const int row0 = m0 + wr * 64 + i * 16 + q16 * 4;
#pragma unroll
        for (int j = 0; j < 4; j++) {
            const int col = n0 + wc * 64 + j * 16 + l15;
            const float bv = bias[col];
#pragma unroll
            for (int r = 0; r < 4; r++) {
                const long idx = (long)(row0 + r) * N + col;
                float v = acc[i][j][r] + bv;
                if (EPI == 1) v = fmaxf(v, 0.f);
                if (EPI == 2) v += resid[idx];
                if (OUT_F32)
                    ((float*)C)[idx] = v;
                else
                    ((u16*)C)[idx] = f2bf(v);
            }
        }
    }
}

// ---------------------------------------------------------------------------
extern "C" void kernel_launch(void* const* d_in, const int* in_sizes, int n_in,
                              void* d_out, int out_size, void* d_ws, size_t ws_size,
                              hipStream_t stream) {
    const float* x = (const float*)d_in[0];
    const float* w_lin = (const float*)d_in[1];
    const float* b_lin = (const float*)d_in[2];
    const float* w1 = (const float*)d_in[3];
    const float* b1 = (const float*)d_in[4];
    const float* w2 = (const float*)d_in[5];
    const float* b2 = (const float*)d_in[6];
    const float* g1 = (const float*)d_in[7];
    const float* be1 = (const float*)d_in[8];
    const float* g2 = (const float*)d_in[9];
    const float* be2 = (const float*)d_in[10];
    float* out = (float*)d_out;

    char* ws = (char*)d_ws;
    const size_t MB = 1024 * 1024;
    u16* y = (u16*)(ws);                       // LN output bf16, 32 MB
    float* x1 = (float*)(ws + 32 * MB);        // attn residual fp32, 64 MB
    u16* h = (u16*)(ws + 96 * MB);             // FF hidden bf16, 128 MB
    u16* z = h;                                // projection bf16, 32 MB (aliases h; z dies before h is written)
    u16* wb_lin = (u16*)(ws + 224 * MB);       // bf16 weights
    u16* wb1 = (u16*)(ws + 225 * MB);
    u16* wb2 = (u16*)(ws + 228 * MB);

    // 0) convert weights fp32 -> bf16
    cvt_kernel<<<(DMODEL * DMODEL) / 1024, 256, 0, stream>>>(w_lin, wb_lin, DMODEL * DMODEL);
    cvt_kernel<<<(FFDIM * DMODEL) / 1024, 256, 0, stream>>>(w1, wb1, FFDIM * DMODEL);
    cvt_kernel<<<(DMODEL * FFDIM) / 1024, 256, 0, stream>>>(w2, wb2, DMODEL * FFDIM);

    // 1) y = LN(x; g1, be1)
    ln_kernel<<<NTOK / 4, 256, 0, stream>>>(x, g1, be1, y);
    // 2) z = y @ w_lin^T + b_lin
    gemm128<0, false><<<dim3(NTOK / BM, DMODEL / BN), 256, 0, stream>>>(y, wb_lin, b_lin, nullptr,
                                                                       z, NTOK, DMODEL, DMODEL);
    // 3+4) x1 = x + W @ z (scan), y = LN(x1; g2, be2) -- fused
    scan_ln_kernel<<<dim3(BATCH, SEQ / SCAN_L), 256, 0, stream>>>(z, x, g2, be2, x1, y);
    // 5) h = relu(y @ w1^T + b1)
    gemm128<1, false><<<dim3(NTOK / BM, FFDIM / BN), 256, 0, stream>>>(y, wb1, b1, nullptr, h,
                                                                      NTOK, FFDIM, DMODEL);
    // 6) out = x1 + h @ w2^T + b2
    gemm128<2, true><<<dim3(NTOK / BM, DMODEL / BN), 256, 0, stream>>>(h, wb2, b2, x1, out,
                                                                      NTOK, DMODEL, FFDIM);
}

// Round 5
// 437.381 us; speedup vs baseline: 1.1568x; 1.1568x over previous
//
#include <hip/hip_runtime.h>

#define SEQ 2048
#define BATCH 16
#define DMODEL 512
#define FFDIM 2048
#define NTOK (SEQ * BATCH) /* 32768 tokens */
#define ALPHA 0.9f

typedef unsigned short u16;
typedef unsigned int u32;
typedef __attribute__((ext_vector_type(8))) short short8;
typedef __attribute__((ext_vector_type(4))) float f32x4;

__device__ __forceinline__ float bf2f(u16 u) {
    unsigned int v = ((unsigned int)u) << 16;
    return __builtin_bit_cast(float, v);
}
__device__ __forceinline__ u16 f2bf(float f) {
    unsigned int v = __builtin_bit_cast(unsigned int, f);
    v += 0x7fffu + ((v >> 16) & 1u);   // RNE
    return (u16)(v >> 16);
}

// ---------------------------------------------------------------------------
// fp32 -> bf16 conversion (weights), 4 elems/thread
// ---------------------------------------------------------------------------
__global__ __launch_bounds__(256) void cvt_kernel(const float* __restrict__ in,
                                                  u16* __restrict__ out, int n) {
    const int i = (blockIdx.x * 256 + threadIdx.x) * 4;
    if (i >= n) return;
    float4 v = *(const float4*)(in + i);
    ushort4 o;
    o.x = f2bf(v.x); o.y = f2bf(v.y); o.z = f2bf(v.z); o.w = f2bf(v.w);
    *(ushort4*)(out + i) = o;
}

// ---------------------------------------------------------------------------
// LayerNorm: one wave per token (64 lanes x 8 elems = 512 = DMODEL)
// fp32 in, bf16 out; fp32 gamma/beta
// ---------------------------------------------------------------------------
__global__ __launch_bounds__(256) void ln_kernel(const float* __restrict__ xin,
                                                 const float* __restrict__ g,
                                                 const float* __restrict__ b,
                                                 u16* __restrict__ y) {
    const int lane = threadIdx.x & 63;
    const int wave = threadIdx.x >> 6;
    const long tok = (long)blockIdx.x * 4 + wave;
    const long off = tok * DMODEL + lane * 8;

    float f[8];
    {
        const float4* xp = (const float4*)(xin + off);
        float4 a = xp[0], c = xp[1];
        f[0] = a.x; f[1] = a.y; f[2] = a.z; f[3] = a.w;
        f[4] = c.x; f[5] = c.y; f[6] = c.z; f[7] = c.w;
    }
    float s = 0.f, s2 = 0.f;
#pragma unroll
    for (int i = 0; i < 8; i++) { s += f[i]; s2 += f[i] * f[i]; }
#pragma unroll
    for (int o = 32; o > 0; o >>= 1) {
        s += __shfl_xor(s, o, 64);
        s2 += __shfl_xor(s2, o, 64);
    }
    const float mean = s * (1.f / DMODEL);
    const float var = s2 * (1.f / DMODEL) - mean * mean;
    const float inv = rsqrtf(var + 1e-5f);

    const float4* gp = (const float4*)(g + lane * 8);
    const float4* bp = (const float4*)(b + lane * 8);
    float4 g0 = gp[0], g1 = gp[1], b0 = bp[0], b1 = bp[1];
    float gg[8] = {g0.x, g0.y, g0.z, g0.w, g1.x, g1.y, g1.z, g1.w};
    float bb[8] = {b0.x, b0.y, b0.z, b0.w, b1.x, b1.y, b1.z, b1.w};
    short8 ov;
#pragma unroll
    for (int i = 0; i < 8; i++)
        ov[i] = (short)f2bf((f[i] - mean) * inv * gg[i] + bb[i]);
    *(short8*)(y + off) = ov;
}

// ---------------------------------------------------------------------------
// Causal exp-decay scan, barrier-free, column-parallel.
// 2 columns/thread (u32 z loads, float2 x loads), SCAN_L=64 / SCAN_H=128
// (alpha^128 ~ 1.4e-6 -> truncation error ~1e-4, under threshold),
// 512 blocks, 4-deep statically-indexed prefetch.
// ROUND-5 FIX: warm-up loop is bounded by runtime nw (0/64/128), NOT a fixed
// SCAN_H trip count (round-4 bug: blocks with s0=64 ran 128 warm-up iters,
// reading z rows >= s0 -> future leakage, absmax ~10). Outer i+=4 loop with
// fully-unrolled inner body keeps all queue indices compile-time (rule #20).
//   r[i] = alpha*(z[i] + r[i-1]);  x1[i] = x[i] + r[i] + c_i*z[i]
//   c_i = 1 - (alpha - alpha^{i+2})/(1-alpha)
// ---------------------------------------------------------------------------
#define SCAN_L 64
#define SCAN_H 128
#define NCOLU (BATCH * DMODEL / 2) /* 4096 u32 columns, row stride 4096 */
__global__ __launch_bounds__(256) void scan_kernel(const u16* __restrict__ z,
                                                   const float* __restrict__ x,
                                                   float* __restrict__ x1) {
    const int colu = blockIdx.x * 256 + threadIdx.x;  // 0..4095
    const int s0 = blockIdx.y * SCAN_L;

    const u32* zp = (const u32*)z;
    const float2* xp = (const float2*)x;
    float2* x1p = (float2*)x1;

    float r0 = 0.f, r1 = 0.f;

    // ---- warm-up: runtime-bounded (nw in {0,64,128}), 4-deep prefetch ----
    {
        int sb = s0 - SCAN_H;
        if (sb < 0) sb = 0;
        const int nw = s0 - sb;
        if (nw > 0) {  // nw >= 64, multiple of 4
            u32 zq[4];
#pragma unroll
            for (int j = 0; j < 4; j++) zq[j] = zp[(long)(sb + j) * NCOLU + colu];
            for (int i = 0; i < nw; i += 4) {
#pragma unroll
                for (int j = 0; j < 4; j++) {
                    const u32 zz = zq[j];
                    if (i + j + 4 < nw)
                        zq[j] = zp[(long)(sb + i + j + 4) * NCOLU + colu];
                    r0 = ALPHA * (bf2f((u16)(zz & 0xffffu)) + r0);
                    r1 = ALPHA * (bf2f((u16)(zz >> 16)) + r1);
                }
            }
        }
    }

    float ap = powf(ALPHA, (float)(s0 + 2));  // alpha^{s0+2}

    // ---- main: 4-deep prefetch of z and x (fixed trip count) ----
    u32 zq[4];
    float2 xq[4];
#pragma unroll
    for (int j = 0; j < 4; j++) {
        zq[j] = zp[(long)(s0 + j) * NCOLU + colu];
        xq[j] = xp[(long)(s0 + j) * NCOLU + colu];
    }
#pragma unroll 4
    for (int i = 0; i < SCAN_L; i++) {
        const int sl = i & 3;  // compile-time per unrolled instance
        const u32 zz = zq[sl];
        const float2 xx = xq[sl];
        if (i + 4 < SCAN_L) {
            zq[sl] = zp[(long)(s0 + i + 4) * NCOLU + colu];
            xq[sl] = xp[(long)(s0 + i + 4) * NCOLU + colu];
        }
        const float z0 = bf2f((u16)(zz & 0xffffu));
        const float z1 = bf2f((u16)(zz >> 16));
        r0 = ALPHA * (z0 + r0);
        r1 = ALPHA * (z1 + r1);
        const float c = 1.f - (ALPHA - ap) * 10.f;  // 10 = 1/(1-alpha)
        ap *= ALPHA;
        x1p[(long)(s0 + i) * NCOLU + colu] = (float2){xx.x + r0 + c * z0, xx.y + r1 + c * z1};
    }
}

// ---------------------------------------------------------------------------
// GEMM 128x128 / BK=64 / 4 waves / 64 KiB LDS -> 2 blocks/CU (cross-block TLP)
//   C[M,N] = epi(A[M,K] @ Bt[N,K]^T + bias[N])
// Tile mapping anchored to the TRUE dispatch index d = bx + by*gx (x fastest).
// Bijective XCD chunking on d, then decode n-fastest:
//   wgid = (d&7)*(nwg/8) + d>>3;  m0 = wgid/gy;  n0 = wgid%gy.
// Same-XCD consecutive blocks share m0 -> A-panel fetched once per XCD,
// re-served from that XCD's L2 to its gy n-siblings.
// Kept: 3-bit octet XOR swizzle (0 bank conflicts, source+read side),
// counted vmcnt(8) depth-1 prefetch, 2 barriers/K-tile.
// EPI: 0=+bias  1=relu(+bias)  2=+bias+resid(fp32);  OUT_F32 selects store type
// ---------------------------------------------------------------------------
#define BM 128
#define BN 128
#define BKK 64

typedef __attribute__((address_space(1))) unsigned int as1_u32;
typedef __attribute__((address_space(3))) unsigned int as3_u32;

__device__ __forceinline__ void gld_lds16(const void* g, const void* l) {
    __builtin_amdgcn_global_load_lds((as1_u32*)(unsigned long long)g,
                                     (as3_u32*)(unsigned int)(unsigned long long)l,
                                     16, 0, 0);
}

template <int EPI, bool OUT_F32>
__global__ __launch_bounds__(256, 2) void gemm128(const u16* __restrict__ A,
                                                  const u16* __restrict__ Bt,
                                                  const float* __restrict__ bias,
                                                  const float* __restrict__ resid,
                                                  void* __restrict__ C,
                                                  int M, int N, int K) {
    __shared__ alignas(16) u16 sA[2][BM * BKK];   // 32 KiB
    __shared__ alignas(16) u16 sB[2][BN * BKK];   // 32 KiB

    const int tid = threadIdx.x;
    const int lane = tid & 63;
    const int wave = tid >> 6;          // 4 waves: 2M x 2N, each owns 64x64
    const int wr = wave >> 1;
    const int wc = wave & 1;
    const int l15 = lane & 15, q16 = lane >> 4;

    // dispatch-anchored bijective XCD swizzle; n-fastest within an XCD chunk
    const int gy = gridDim.y;
    const int nwg = gridDim.x * gy;
    const int d = blockIdx.y * gridDim.x + blockIdx.x;  // HW dispatch order
    const int wgid = (d & 7) * (nwg >> 3) + (d >> 3);
    const int m0 = (wgid / gy) * BM;
    const int n0 = (wgid % gy) * BN;

    // ---- staging: 1024 octets per matrix tile, 256 thr -> 4 chunks each.
    //      LDS dest linear; global source octet pre-swizzled (rule #21). ----
    const u16* gA[4];
    const u16* gB[4];
    int ldsoff[4];
#pragma unroll
    for (int i = 0; i < 4; i++) {
        const int ch = tid + i * 256;           // 0..1023
        const int r = ch >> 3;                  // row 0..127 (8 octets/row)
        const int oo = (ch & 7) ^ (r & 7);      // swizzled source octet
        gA[i] = A + (long)(m0 + r) * K + oo * 8;
        gB[i] = Bt + (long)(n0 + r) * K + oo * 8;
        ldsoff[i] = ch * 8;                     // u16 elements
    }

    // ---- fragment read addressing (swizzled): row&7 == l15&7 for all frags ----
    const int x7 = l15 & 7;
    int octk[2];
    octk[0] = ((0 + q16) ^ x7) * 8;
    octk[1] = ((4 + q16) ^ x7) * 8;
    const int rowA0 = wr * 64 + l15;
    const int rowB0 = wc * 64 + l15;

    f32x4 acc[4][4];
#pragma unroll
    for (int i = 0; i < 4; i++)
#pragma unroll
        for (int j = 0; j < 4; j++) acc[i][j] = (f32x4){0.f, 0.f, 0.f, 0.f};

    const int NT = K / BKK;

    // prologue: stage tile 0 -> buf 0
#pragma unroll
    for (int i = 0; i < 4; i++) gld_lds16(gA[i], &sA[0][ldsoff[i]]);
#pragma unroll
    for (int i = 0; i < 4; i++) gld_lds16(gB[i], &sB[0][ldsoff[i]]);

#pragma unroll 1
    for (int t = 0; t < NT; ++t) {
        const int pb = t & 1;
        // stage t+1 into the other buffer, then counted wait for tile t.
        if (t + 1 < NT) {
            const int pn = (t + 1) & 1;
            const int ko = (t + 1) * BKK;
#pragma unroll
            for (int i = 0; i < 4; i++) gld_lds16(gA[i] + ko, &sA[pn][ldsoff[i]]);
#pragma unroll
            for (int i = 0; i < 4; i++) gld_lds16(gB[i] + ko, &sB[pn][ldsoff[i]]);
            asm volatile("s_waitcnt vmcnt(8)" ::: "memory");
        } else {
            asm volatile("s_waitcnt vmcnt(0)" ::: "memory");
        }
        __builtin_amdgcn_s_barrier();   // all waves' tile-t loads landed

        const u16* pa = &sA[pb][rowA0 * BKK];
        const u16* pbb = &sB[pb][rowB0 * BKK];

#pragma unroll
        for (int kk = 0; kk < 2; kk++) {
            short8 a[4], b[4];
#pragma unroll
            for (int i = 0; i < 4; i++)
                a[i] = *(const short8*)(pa + i * 16 * BKK + octk[kk]);
#pragma unroll
            for (int j = 0; j < 4; j++)
                b[j] = *(const short8*)(pbb + j * 16 * BKK + octk[kk]);
#pragma unroll
            for (int i = 0; i < 4; i++)
#pragma unroll
                for (int j = 0; j < 4; j++)
                    acc[i][j] = __builtin_amdgcn_mfma_f32_16x16x32_bf16(a[i], b[j],
                                                                        acc[i][j], 0, 0, 0);
        }
        __builtin_amdgcn_s_barrier();   // done reading buf[pb] before restage
    }

    // ---- epilogue: C/D layout col=lane&15, row=(lane>>4)*4+reg ----
#pragma unroll
    for (int i = 0; i < 4; i++) {
        const int row0 = m0 + wr * 64 + i * 16 + q16 * 4;
#pragma unroll
        for (int j = 0; j < 4; j++) {
            const int col = n0 + wc * 64 + j * 16 + l15;
            const float bv = bias[col];
#pragma unroll
            for (int r = 0; r < 4; r++) {
                const long idx = (long)(row0 + r) * N + col;
                float v = acc[i][j][r] + bv;
                if (EPI == 1) v = fmaxf(v, 0.f);
                if (EPI == 2) v += resid[idx];
                if (OUT_F32)
                    ((float*)C)[idx] = v;
                else
                    ((u16*)C)[idx] = f2bf(v);
            }
        }
    }
}

// ---------------------------------------------------------------------------
extern "C" void kernel_launch(void* const* d_in, const int* in_sizes, int n_in,
                              void* d_out, int out_size, void* d_ws, size_t ws_size,
                              hipStream_t stream) {
    const float* x = (const float*)d_in[0];
    const float* w_lin = (const float*)d_in[1];
    const float* b_lin = (const float*)d_in[2];
    const float* w1 = (const float*)d_in[3];
    const float* b1 = (const float*)d_in[4];
    const float* w2 = (const float*)d_in[5];
    const float* b2 = (const float*)d_in[6];
    const float* g1 = (const float*)d_in[7];
    const float* be1 = (const float*)d_in[8];
    const float* g2 = (const float*)d_in[9];
    const float* be2 = (const float*)d_in[10];
    float* out = (float*)d_out;

    char* ws = (char*)d_ws;
    const size_t MB = 1024 * 1024;
    u16* y = (u16*)(ws);                       // LN output bf16, 32 MB
    float* x1 = (float*)(ws + 32 * MB);        // attn residual fp32, 64 MB
    u16* h = (u16*)(ws + 96 * MB);             // FF hidden bf16, 128 MB
    u16* z = h;                                // projection bf16, 32 MB (aliases h; z dies before h is written)
    u16* wb_lin = (u16*)(ws + 224 * MB);       // bf16 weights
    u16* wb1 = (u16*)(ws + 225 * MB);
    u16* wb2 = (u16*)(ws + 228 * MB);

    // 0) convert weights fp32 -> bf16
    cvt_kernel<<<(DMODEL * DMODEL) / 1024, 256, 0, stream>>>(w_lin, wb_lin, DMODEL * DMODEL);
    cvt_kernel<<<(FFDIM * DMODEL) / 1024, 256, 0, stream>>>(w1, wb1, FFDIM * DMODEL);
    cvt_kernel<<<(DMODEL * FFDIM) / 1024, 256, 0, stream>>>(w2, wb2, DMODEL * FFDIM);

    // 1) y = LN(x; g1, be1)
    ln_kernel<<<NTOK / 4, 256, 0, stream>>>(x, g1, be1, y);
    // 2) z = y @ w_lin^T + b_lin
    gemm128<0, false><<<dim3(NTOK / BM, DMODEL / BN), 256, 0, stream>>>(y, wb_lin, b_lin, nullptr,
                                                                       z, NTOK, DMODEL, DMODEL);
    // 3) x1 = x + W @ z   (exp-decay scan)
    scan_kernel<<<dim3(NCOLU / 256, SEQ / SCAN_L), 256, 0, stream>>>(z, x, x1);
    // 4) y = LN(x1; g2, be2)
    ln_kernel<<<NTOK / 4, 256, 0, stream>>>(x1, g2, be2, y);
    // 5) h = relu(y @ w1^T + b1)
    gemm128<1, false><<<dim3(NTOK / BM, FFDIM / BN), 256, 0, stream>>>(y, wb1, b1, nullptr, h,
                                                                      NTOK, FFDIM, DMODEL);
    // 6) out = x1 + h @ w2^T + b2
    gemm128<2, true><<<dim3(NTOK / BM, DMODEL / BN), 256, 0, stream>>>(h, wb2, b2, x1, out,
                                                                      NTOK, DMODEL, FFDIM);
}